// Round 5
// baseline (834.547 us; speedup 1.0000x reference)
//
#include <hip/hip_runtime.h>
#include <cstddef>
#include <cstdint>

// ---------------------------------------------------------------------------
// LocalAttentionFusion — MFMA, 2 ROIs/block, 8 waves (2 M-grp x 4 oc-grp).
// ROI-extract -> CAT2[ba][81][512] bf16 (zero-padded 9x9, channel-innermost)
// conv1 3x3 512->256 (MFMA implicit GEMM) -> X2[ba][81][256] bf16 padded
// conv2 3x3 256->256 (MFMA)               -> X3[ba][256][49] bf16
// head: 1x1(256->64)+ReLU -> 1x1(64->2) -> softmax -> blend (fp32 scalar)
// ---------------------------------------------------------------------------

typedef unsigned int u32;
typedef unsigned short u16;
typedef __attribute__((ext_vector_type(8))) short short8;   // 8 bf16 = 4 VGPR
typedef __attribute__((ext_vector_type(4))) float float4v;  // MFMA acc

__device__ __forceinline__ float bf2f(u16 u) {
  u32 x = ((u32)u) << 16;
  return __builtin_bit_cast(float, x);
}
__device__ __forceinline__ u16 f2bf(float f) {
  u32 x = __builtin_bit_cast(u32, f);
  x = x + 0x7fffu + ((x >> 16) & 1u);  // RNE
  return (u16)(x >> 16);
}
__device__ __forceinline__ void gl_lds16(const void* g, void* l) {
  __builtin_amdgcn_global_load_lds((const __attribute__((address_space(1))) void*)g,
                                   (__attribute__((address_space(3))) void*)l, 16, 0, 0);
}

// ---- prep: conv weights OIHW -> [tap][oc][ic] bf16 ------------------------
template <int IC>
__global__ void k_prep_w(const float* __restrict__ w, u16* __restrict__ wt) {
  int i = blockIdx.x * 256 + threadIdx.x;
  if (i >= 9 * 256 * IC) return;
  int t = i / (256 * IC);
  int rem = i - t * 256 * IC;
  int oc = rem / IC, ic = rem - oc * IC;
  wt[i] = f2bf(w[((size_t)oc * IC + ic) * 9 + t]);
}

// ---- prep: fold conv bias + BN into per-channel scale/bias ----------------
__global__ void k_prep_bn(const float* __restrict__ cb, const float* __restrict__ sc,
                          const float* __restrict__ bi, const float* __restrict__ mn,
                          const float* __restrict__ vr, float* __restrict__ sb) {
  int c = threadIdx.x;  // 256 threads
  float inv = sc[c] * rsqrtf(vr[c] + 1e-5f);
  sb[c]       = inv;
  sb[256 + c] = cb[c] * inv + (bi[c] - mn[c] * inv);
}

// ---- ROI extraction -> CAT2[ba][81][512] bf16, zero border ----------------
__global__ __launch_bounds__(256)
void k_roi2(const float* __restrict__ frgb, const float* __restrict__ ftir,
            const int* __restrict__ coords, u16* __restrict__ cat) {
  int ba = blockIdx.x, b = ba >> 7, tid = threadIdx.x;
  __shared__ int   si0[2][7], si1[2][7];
  __shared__ float sw0[2][7], sw1[2][7];
  __shared__ u16 tile[49][514];  // [pixel][channel], stride 514 for bank spread
  if (tid < 14) {
    int axis = tid / 7;  // 0 = y (coords[...,1]), 1 = x (coords[...,0])
    int j = tid - axis * 7;
    int c = coords[ba * 2 + (axis == 0 ? 1 : 0)];
    int start = max(0, c - 3);
    int end   = min(64, c + 4);
    int Li = end - start;
    float L = (float)Li;
    float src = ((float)j + 0.5f) * L / 7.0f - 0.5f;
    src = fminf(fmaxf(src, 0.0f), L - 1.0f);
    int i0 = (int)floorf(src);
    int i1 = min(i0 + 1, Li - 1);
    float w1 = src - (float)i0;
    si0[axis][j] = start + i0;
    si1[axis][j] = start + i1;
    sw0[axis][j] = 1.0f - w1;
    sw1[axis][j] = w1;
  }
  __syncthreads();
  const float* fr = frgb + (size_t)b * 256 * 4096;
  const float* ft = ftir + (size_t)b * 256 * 4096;
  for (int idx = tid; idx < 256 * 49; idx += 256) {
    int c = idx / 49, p = idx - c * 49;
    int jy = p / 7, jx = p - (p / 7) * 7;
    int y0 = si0[0][jy], y1 = si1[0][jy];
    int x0 = si0[1][jx], x1 = si1[1][jx];
    float wy0 = sw0[0][jy], wy1 = sw1[0][jy];
    float wx0 = sw0[1][jx], wx1 = sw1[1][jx];
    float a00 = wy0 * wx0, a01 = wy0 * wx1, a10 = wy1 * wx0, a11 = wy1 * wx1;
    const float* fc = fr + (size_t)c * 4096;
    float vr_ = a00 * fc[y0 * 64 + x0] + a01 * fc[y0 * 64 + x1] +
                a10 * fc[y1 * 64 + x0] + a11 * fc[y1 * 64 + x1];
    const float* gc = ft + (size_t)c * 4096;
    float vt_ = a00 * gc[y0 * 64 + x0] + a01 * gc[y0 * 64 + x1] +
                a10 * gc[y1 * 64 + x0] + a11 * gc[y1 * 64 + x1];
    tile[p][c]       = f2bf(vr_);
    tile[p][256 + c] = f2bf(vt_);
  }
  __syncthreads();
  u16* dst = cat + (size_t)ba * 81 * 512;
  for (int o = tid; o < 81 * 512; o += 256) {
    int row = o >> 9, c = o & 511;
    int py0 = row / 9, px0 = row - (row / 9) * 9;
    u16 v = 0;
    if (py0 >= 1 && py0 <= 7 && px0 >= 1 && px0 <= 7)
      v = tile[(py0 - 1) * 7 + (px0 - 1)][c];
    dst[o] = v;
  }
}

// ---- MFMA 3x3 conv + BN + ReLU, 2 ROIs/block, 8 waves ----------------------
// IN:  [ba][81][ICT] bf16, zero-bordered.  WT: [tap][256][ICT] bf16.
// FIRST: OUT = [ba][81][256] bf16 padded (borders zeroed here).
// else:  OUT = [ba][256][49] bf16.
// Block: 512 thr = 8 waves.  wave: ng = wv&3 -> oc slice ng*64 (f=4 frags);
// mg = wv>>2 -> M-tiles pfg = 2*pfl + mg (mg0: 0,2,4,6; mg1: 1,3,5).
// M-tile = 14 px (2 image rows), lanes 14,15 dup lanes 0,1 (broadcast).
// LDS: [2 buf][2 roi][81 rows][64 ic] bf16, XOR-swizzled (byte^=(row&7)<<4).
template <int ICT, bool FIRST>
__global__ __launch_bounds__(512, 4)
void k_conv_mfma(const u16* __restrict__ IN, const u16* __restrict__ WT,
                 const float* __restrict__ sb, u16* __restrict__ OUT) {
  constexpr int NC = ICT / 64;       // 64-ic chunks
  constexpr int BUFB = 2 * 81 * 128; // bytes per buffer (2 roi x 81 x 128B)
  __shared__ __align__(16) u16 lds[2][BUFB / 2];
  const int tid = threadIdx.x;
  const int lane = tid & 63, wv = tid >> 6;          // wv 0..7
  const int ng = wv & 3, mg = wv >> 2;
  const int l15 = lane & 15, hi = lane >> 4;
  const int ba2 = blockIdx.x * 2;
  const char* inb = (const char*)IN;

  if (FIRST) {  // zero the 32 border rows of both padded outputs
    int oc = tid & 255, rh = tid >> 8;
    u16* ob = OUT + ((size_t)(ba2 + rh) * 81) * 256 + oc;
#pragma unroll
    for (int i = 0; i < 32; ++i) {
      int row = (i < 9) ? i : (i < 18) ? (63 + i)
                                       : (9 * ((i - 18) / 2 + 1) + ((i - 18) & 1) * 8);
      ob[row * 256] = 0;
    }
  }

  // A-fragment row base per local M-tile: pixel P = 14*pfg + lp
  int rg[4];
  {
    int lp = (l15 < 14) ? l15 : (l15 - 14);
#pragma unroll
    for (int pfl = 0; pfl < 4; ++pfl) {
      int pfg = 2 * pfl + mg;
      if (pfg > 6) pfg = 0;  // inactive tile (mg1,pfl3): clamped, never used
      int P = 14 * pfg + lp;
      int roi = (P >= 49) ? 1 : 0;
      int q = P - roi * 49;
      rg[pfl] = roi * 81 + (q / 7) * 9 + (q - (q / 7) * 7);
    }
  }

  float4v acc[4][4];
#pragma unroll
  for (int a = 0; a < 4; ++a)
#pragma unroll
    for (int f = 0; f < 4; ++f) acc[a][f] = (float4v){0.f, 0.f, 0.f, 0.f};

  auto stage = [&](int ch, int buf) {
    for (int s = wv; s < 21; s += 8) {         // 1024B segments
      int d = s * 1024 + lane * 16;            // linear dest byte in buffer
      if (d < BUFB) {
        int u = d ^ (((d >> 7) & 7) << 4);     // inverse swizzle on source
        int row_g = u >> 7;                    // 0..161
        int col = u & 127;
        int roi = (row_g >= 81) ? 1 : 0;
        int rr = row_g - roi * 81;
        const char* src = inb + ((size_t)(ba2 + roi) * 81 + rr) * (ICT * 2) +
                          ch * 128 + col;
        gl_lds16(src, (char*)&lds[buf][0] + s * 1024);
      }
    }
  };

  stage(0, 0);
  __syncthreads();

  // per-thread weight base: oc = ng*64 + f*16 + l15, k-offset hi*8
  const u16* wthr = WT + ((size_t)(ng * 64 + l15)) * ICT + hi * 8;

  int cur = 0;
#pragma unroll 1
  for (int ch = 0; ch < NC; ++ch) {
    if (ch + 1 < NC) stage(ch + 1, cur ^ 1);
    const char* lb = (const char*)&lds[cur][0];
    const int chk = ch * 64;
    short8 wfr[2][4];
#pragma unroll
    for (int f = 0; f < 4; ++f)
      wfr[0][f] = *(const short8*)(wthr + (size_t)(f * 16) * ICT + chk);
#pragma unroll
    for (int j = 0; j < 18; ++j) {
      const int t = j >> 1, kk = j & 1;
      const int dy = t / 3, dx = t - (t / 3) * 3;
      if (j < 17) {  // prefetch next (t,kk) weights, issued before ds_reads
        const int t2 = (j + 1) >> 1, k2 = (j + 1) & 1;
#pragma unroll
        for (int f = 0; f < 4; ++f)
          wfr[(j + 1) & 1][f] =
              *(const short8*)(wthr + (size_t)(t2 * 256 + f * 16) * ICT + chk + k2 * 32);
      }
      short8 bfr[4];
#pragma unroll
      for (int pfl = 0; pfl < 4; ++pfl) {
        if (pfl == 3 && mg != 0) continue;     // wave-uniform skip
        int rr = rg[pfl] + dy * 9 + dx;
        int byt = (rr * 128 + kk * 64 + hi * 16) ^ ((rr & 7) << 4);
        bfr[pfl] = *(const short8*)(lb + byt);
      }
      __builtin_amdgcn_s_setprio(1);
#pragma unroll
      for (int pfl = 0; pfl < 4; ++pfl) {
        if (pfl == 3 && mg != 0) continue;     // wave-uniform skip
#pragma unroll
        for (int f = 0; f < 4; ++f)
          acc[pfl][f] = FIRST
              ? __builtin_amdgcn_mfma_f32_16x16x32_bf16(bfr[pfl], wfr[j & 1][f],
                                                        acc[pfl][f], 0, 0, 0)
              : __builtin_amdgcn_mfma_f32_16x16x32_bf16(wfr[j & 1][f], bfr[pfl],
                                                        acc[pfl][f], 0, 0, 0);
      }
      __builtin_amdgcn_s_setprio(0);
    }
    __syncthreads();  // drains global_load_lds for next buffer
    cur ^= 1;
  }

  if (FIRST) {
    // D: row = pixel-in-tile (hi*4+reg), col = oc (ng*64 + f*16 + l15)
    u16* ob = OUT + (size_t)ba2 * 81 * 256;
#pragma unroll
    for (int f = 0; f < 4; ++f) {
      int oc = ng * 64 + f * 16 + l15;
      float s = sb[oc], bb = sb[256 + oc];
#pragma unroll
      for (int pfl = 0; pfl < 4; ++pfl) {
        if (pfl == 3 && mg != 0) continue;
        int pfg = 2 * pfl + mg;
#pragma unroll
        for (int reg = 0; reg < 4; ++reg) {
          int r = hi * 4 + reg;
          if (r < 14) {
            int P = 14 * pfg + r;
            int roi = (P >= 49) ? 1 : 0;
            int q = P - roi * 49;
            int pp = (q / 7 + 1) * 9 + (q - (q / 7) * 7) + 1;
            ob[((size_t)roi * 81 + pp) * 256 + oc] =
                f2bf(fmaxf(acc[pfl][f][reg] * s + bb, 0.0f));
          }
        }
      }
    }
  } else {
    // D: row = oc (ng*64 + f*16 + hi*4 + reg), col = pixel-in-tile (l15)
    u16* ob = OUT + (size_t)ba2 * 256 * 49;
    if (l15 < 14) {
#pragma unroll
      for (int f = 0; f < 4; ++f)
#pragma unroll
        for (int reg = 0; reg < 4; ++reg) {
          int oc = ng * 64 + f * 16 + hi * 4 + reg;
          float s = sb[oc], bb = sb[256 + oc];
#pragma unroll
          for (int pfl = 0; pfl < 4; ++pfl) {
            if (pfl == 3 && mg != 0) continue;
            int pfg = 2 * pfl + mg;
            int P = 14 * pfg + l15;
            int roi = (P >= 49) ? 1 : 0;
            int q = P - roi * 49;
            ob[((size_t)roi * 256 + oc) * 49 + q] =
                f2bf(fmaxf(acc[pfl][f][reg] * s + bb, 0.0f));
          }
        }
    }
  }
}

// ---- head: 1x1(256->64)+ReLU -> 1x1(64->2) -> softmax -> blend ------------
__global__ __launch_bounds__(256)
void k_head_fuse(const u16* __restrict__ x3, const u16* __restrict__ cat,
                 const float* __restrict__ w1, const float* __restrict__ b1,
                 const float* __restrict__ w2, const float* __restrict__ b2,
                 float* __restrict__ out) {
  int ba  = blockIdx.x;
  int tid = threadIdx.x;
  __shared__ float xs[256 * 49];
  __shared__ float hs[64 * 49];
  __shared__ float ls[2 * 49];
  __shared__ float swx[2 * 49];
  const u16* src = x3 + (size_t)ba * 256 * 49;
  for (int idx = tid; idx < 256 * 49; idx += 256) xs[idx] = bf2f(src[idx]);
  __syncthreads();
  for (int idx = tid; idx < 64 * 49; idx += 256) {
    int oh = idx / 49, p = idx - oh * 49;
    float s = b1[oh];
    const float* wr = w1 + oh * 256;
    for (int ic = 0; ic < 256; ++ic) s += wr[ic] * xs[ic * 49 + p];
    hs[idx] = fmaxf(s, 0.0f);
  }
  __syncthreads();
  if (tid < 98) {
    int chn = tid / 49, p = tid - chn * 49;
    float s = b2[chn];
    const float* wr = w2 + chn * 64;
    for (int k = 0; k < 64; ++k) s += wr[k] * hs[k * 49 + p];
    ls[tid] = s;
  }
  __syncthreads();
  if (tid < 49) {
    float l0 = ls[tid], l1 = ls[49 + tid];
    float m = fmaxf(l0, l1);
    float e0 = expf(l0 - m), e1 = expf(l1 - m);
    float d = e0 + e1;
    swx[tid]      = e0 / d;
    swx[49 + tid] = e1 / d;
  }
  __syncthreads();
  const u16* cr = cat + (size_t)ba * 81 * 512;
  float* o = out + (size_t)ba * 256 * 49;
  for (int idx = tid; idx < 256 * 49; idx += 256) {
    int c = idx / 49, p = idx - (idx / 49) * 49;
    int pp = (p / 7 + 1) * 9 + (p - (p / 7) * 7) + 1;
    float rgb = bf2f(cr[pp * 512 + c]);
    float tir = bf2f(cr[pp * 512 + 256 + c]);
    o[idx] = swx[p] * rgb + swx[49 + p] * tir;
  }
}

// ---------------------------------------------------------------------------
extern "C" void kernel_launch(void* const* d_in, const int* in_sizes, int n_in,
                              void* d_out, int out_size, void* d_ws, size_t ws_size,
                              hipStream_t stream) {
  const float* feat_rgb = (const float*)d_in[0];
  const float* feat_tir = (const float*)d_in[1];
  const int*   coords   = (const int*)d_in[2];
  const float* conv1_w  = (const float*)d_in[3];
  const float* conv1_b  = (const float*)d_in[4];
  const float* bn1_s    = (const float*)d_in[5];
  const float* bn1_b    = (const float*)d_in[6];
  const float* bn1_m    = (const float*)d_in[7];
  const float* bn1_v    = (const float*)d_in[8];
  const float* conv2_w  = (const float*)d_in[9];
  const float* conv2_b  = (const float*)d_in[10];
  const float* bn2_s    = (const float*)d_in[11];
  const float* bn2_b    = (const float*)d_in[12];
  const float* bn2_m    = (const float*)d_in[13];
  const float* bn2_v    = (const float*)d_in[14];
  const float* wg1_w    = (const float*)d_in[15];
  const float* wg1_b    = (const float*)d_in[16];
  const float* wg2_w    = (const float*)d_in[17];
  const float* wg2_b    = (const float*)d_in[18];
  float* out = (float*)d_out;

  // workspace layout (bytes)
  char* base = (char*)d_ws;
  u16*   W1T  = (u16*)(base);                       //  2,359,296 B
  u16*   W2T  = (u16*)(base + 2359296);             //  1,179,648 B
  float* SB1  = (float*)(base + 2359296 + 1179648); //      2,048 B
  float* SB2  = (float*)(base + 2359296 + 1179648 + 2048);
  u16*   CAT2 = (u16*)(base + 2359296 + 1179648 + 4096);                       // 84,934,656 B
  u16*   X2   = (u16*)(base + 2359296 + 1179648 + 4096 + 84934656);            // 42,467,328 B
  u16*   X3   = (u16*)(base + 2359296 + 1179648 + 4096 + 84934656 + 42467328); // 25,690,112 B
  // total ~156.6 MB

  k_prep_w<512><<<(9 * 256 * 512 + 255) / 256, 256, 0, stream>>>(conv1_w, W1T);
  k_prep_w<256><<<(9 * 256 * 256 + 255) / 256, 256, 0, stream>>>(conv2_w, W2T);
  k_prep_bn<<<1, 256, 0, stream>>>(conv1_b, bn1_s, bn1_b, bn1_m, bn1_v, SB1);
  k_prep_bn<<<1, 256, 0, stream>>>(conv2_b, bn2_s, bn2_b, bn2_m, bn2_v, SB2);
  k_roi2<<<1024, 256, 0, stream>>>(feat_rgb, feat_tir, coords, CAT2);
  k_conv_mfma<512, true><<<512, 512, 0, stream>>>(CAT2, W1T, SB1, X2);
  k_conv_mfma<256, false><<<512, 512, 0, stream>>>(X2, W2T, SB2, X3);
  k_head_fuse<<<1024, 256, 0, stream>>>(X3, CAT2, wg1_w, wg1_b, wg2_w, wg2_b, out);
}

// Round 6
// 616.869 us; speedup vs baseline: 1.3529x; 1.3529x over previous
//
#include <hip/hip_runtime.h>
#include <cstddef>
#include <cstdint>

// ---------------------------------------------------------------------------
// LocalAttentionFusion — MFMA 32x32x16, 2 ROIs/block, 8 waves (4 ng x 2 mg).
// ROI-extract -> CAT2[ba][81][512] bf16 (zero-padded 9x9, channel-innermost)
// conv1 3x3 512->256 (MFMA implicit GEMM) -> X2[ba][81][256] bf16 padded
// conv2 3x3 256->256 (MFMA)               -> X3[ba][256][49] bf16
// head: 1x1(256->64)+ReLU -> 1x1(64->2) -> softmax -> blend (fp32 scalar)
// ---------------------------------------------------------------------------

typedef unsigned int u32;
typedef unsigned short u16;
typedef __attribute__((ext_vector_type(8))) short short8;     // 8 bf16 = 4 VGPR
typedef __attribute__((ext_vector_type(16))) float float16v;  // 32x32 MFMA acc

__device__ __forceinline__ float bf2f(u16 u) {
  u32 x = ((u32)u) << 16;
  return __builtin_bit_cast(float, x);
}
__device__ __forceinline__ u16 f2bf(float f) {
  u32 x = __builtin_bit_cast(u32, f);
  x = x + 0x7fffu + ((x >> 16) & 1u);  // RNE
  return (u16)(x >> 16);
}
__device__ __forceinline__ void gl_lds16(const void* g, void* l) {
  __builtin_amdgcn_global_load_lds((const __attribute__((address_space(1))) void*)g,
                                   (__attribute__((address_space(3))) void*)l, 16, 0, 0);
}

// ---- prep: conv weights OIHW -> [tap][ic/8][256 oc][8 ic] bf16 ------------
// Fragment (tap, ic-octet, 32 oc) is 2 contiguous 512B runs -> coalesced.
template <int IC>
__global__ void k_prep_w(const float* __restrict__ w, u16* __restrict__ wt) {
  int i = blockIdx.x * 256 + threadIdx.x;
  if (i >= 9 * 256 * IC) return;
  int e = i & 7;
  int r = i >> 3;
  int oc = r & 255;
  int r2 = r >> 8;
  int oct = r2 % (IC / 8);
  int t = r2 / (IC / 8);
  int ic = oct * 8 + e;
  wt[i] = f2bf(w[((size_t)oc * IC + ic) * 9 + t]);
}

// ---- prep: fold conv bias + BN into per-channel scale/bias ----------------
__global__ void k_prep_bn(const float* __restrict__ cb, const float* __restrict__ sc,
                          const float* __restrict__ bi, const float* __restrict__ mn,
                          const float* __restrict__ vr, float* __restrict__ sb) {
  int c = threadIdx.x;  // 256 threads
  float inv = sc[c] * rsqrtf(vr[c] + 1e-5f);
  sb[c]       = inv;
  sb[256 + c] = cb[c] * inv + (bi[c] - mn[c] * inv);
}

// ---- ROI extraction -> CAT2[ba][81][512] bf16, zero border ----------------
__global__ __launch_bounds__(256)
void k_roi2(const float* __restrict__ frgb, const float* __restrict__ ftir,
            const int* __restrict__ coords, u16* __restrict__ cat) {
  int ba = blockIdx.x, b = ba >> 7, tid = threadIdx.x;
  __shared__ int   si0[2][7], si1[2][7];
  __shared__ float sw0[2][7], sw1[2][7];
  __shared__ u16 tile[49][514];  // [pixel][channel], stride 514 for bank spread
  if (tid < 14) {
    int axis = tid / 7;  // 0 = y (coords[...,1]), 1 = x (coords[...,0])
    int j = tid - axis * 7;
    int c = coords[ba * 2 + (axis == 0 ? 1 : 0)];
    int start = max(0, c - 3);
    int end   = min(64, c + 4);
    int Li = end - start;
    float L = (float)Li;
    float src = ((float)j + 0.5f) * L / 7.0f - 0.5f;
    src = fminf(fmaxf(src, 0.0f), L - 1.0f);
    int i0 = (int)floorf(src);
    int i1 = min(i0 + 1, Li - 1);
    float w1 = src - (float)i0;
    si0[axis][j] = start + i0;
    si1[axis][j] = start + i1;
    sw0[axis][j] = 1.0f - w1;
    sw1[axis][j] = w1;
  }
  __syncthreads();
  const float* fr = frgb + (size_t)b * 256 * 4096;
  const float* ft = ftir + (size_t)b * 256 * 4096;
  for (int idx = tid; idx < 256 * 49; idx += 256) {
    int c = idx / 49, p = idx - c * 49;
    int jy = p / 7, jx = p - (p / 7) * 7;
    int y0 = si0[0][jy], y1 = si1[0][jy];
    int x0 = si0[1][jx], x1 = si1[1][jx];
    float wy0 = sw0[0][jy], wy1 = sw1[0][jy];
    float wx0 = sw0[1][jx], wx1 = sw1[1][jx];
    float a00 = wy0 * wx0, a01 = wy0 * wx1, a10 = wy1 * wx0, a11 = wy1 * wx1;
    const float* fc = fr + (size_t)c * 4096;
    float vr_ = a00 * fc[y0 * 64 + x0] + a01 * fc[y0 * 64 + x1] +
                a10 * fc[y1 * 64 + x0] + a11 * fc[y1 * 64 + x1];
    const float* gc = ft + (size_t)c * 4096;
    float vt_ = a00 * gc[y0 * 64 + x0] + a01 * gc[y0 * 64 + x1] +
                a10 * gc[y1 * 64 + x0] + a11 * gc[y1 * 64 + x1];
    tile[p][c]       = f2bf(vr_);
    tile[p][256 + c] = f2bf(vt_);
  }
  __syncthreads();
  u16* dst = cat + (size_t)ba * 81 * 512;
  for (int o = tid; o < 81 * 512; o += 256) {
    int row = o >> 9, c = o & 511;
    int py0 = row / 9, px0 = row - (row / 9) * 9;
    u16 v = 0;
    if (py0 >= 1 && py0 <= 7 && px0 >= 1 && px0 <= 7)
      v = tile[(py0 - 1) * 7 + (px0 - 1)][c];
    dst[o] = v;
  }
}

// ---- MFMA 3x3 conv + BN + ReLU, 32x32x16, 2 ROIs/block, 8 waves ------------
// IN:  [ba][81][ICT] bf16, zero-bordered.  WT: [tap][ICT/8][256][8] bf16.
// FIRST: OUT = [ba][81][256] bf16 padded (borders zeroed here).
// else:  OUT = [ba][256][49] bf16.
// Waves: ng = wv&3 -> 64 oc (2 n-frags of 32); mg = wv>>2 -> 2 M-tiles of
// 32 px (tl = mg*2 + i).  M padded 98->128 (tile 3 mostly dead).
// LDS: [2 buf][2 roi][81 rows][64 ic] bf16, XOR-swizzled (byte^=(row&7)<<4).
template <int ICT, bool FIRST>
__global__ __launch_bounds__(512, 4)
void k_conv_mfma(const u16* __restrict__ IN, const u16* __restrict__ WT,
                 const float* __restrict__ sb, u16* __restrict__ OUT) {
  constexpr int NC = ICT / 64;       // 64-ic chunks
  constexpr int BUFB = 2 * 81 * 128; // bytes per buffer (2 roi x 81 x 128B)
  __shared__ __align__(16) u16 lds[2][BUFB / 2];
  const int tid = threadIdx.x;
  const int lane = tid & 63, wv = tid >> 6;          // wv 0..7
  const int ng = wv & 3, mg = wv >> 2;
  const int l31 = lane & 31, h32 = lane >> 5;
  const int ba2 = blockIdx.x * 2;
  const char* inb = (const char*)IN;

  if (FIRST) {  // zero the 32 border rows of both padded outputs
    int oc = tid & 255, rh = tid >> 8;
    u16* ob = OUT + ((size_t)(ba2 + rh) * 81) * 256 + oc;
#pragma unroll
    for (int i = 0; i < 32; ++i) {
      int row = (i < 9) ? i : (i < 18) ? (63 + i)
                                       : (9 * ((i - 18) / 2 + 1) + ((i - 18) & 1) * 8);
      ob[row * 256] = 0;
    }
  }

  // A-row base per local M-tile: pixel P = (mg*2+i)*32 + l31, clamp 97
  int rg[2];
#pragma unroll
  for (int i = 0; i < 2; ++i) {
    int P = (mg * 2 + i) * 32 + l31;
    if (P > 97) P = 97;
    int roi = (P >= 49) ? 1 : 0;
    int q = P - roi * 49;
    rg[i] = roi * 81 + (q / 7) * 9 + (q - (q / 7) * 7);
  }

  float16v acc[2][2];  // [tile][f]
#pragma unroll
  for (int i = 0; i < 2; ++i)
#pragma unroll
    for (int f = 0; f < 2; ++f)
#pragma unroll
      for (int e = 0; e < 16; ++e) acc[i][f][e] = 0.0f;

  auto stage = [&](int ch, int buf) {
    for (int s = wv; s < 21; s += 8) {         // 1024B segments
      int d = s * 1024 + lane * 16;            // linear dest byte in buffer
      if (d < BUFB) {
        int u = d ^ (((d >> 7) & 7) << 4);     // inverse swizzle on source
        int row_g = u >> 7;                    // 0..161
        int col = u & 127;
        int roi = (row_g >= 81) ? 1 : 0;
        int rr = row_g - roi * 81;
        const char* src = inb + ((size_t)(ba2 + roi) * 81 + rr) * (ICT * 2) +
                          ch * 128 + col;
        gl_lds16(src, (char*)&lds[buf][0] + s * 1024);
      }
    }
  };

  stage(0, 0);
  __syncthreads();

  // weight: elem = (t*(ICT/8) + ch*8 + kk*2 + h32)*2048 + (ng*64 + f*32 + l31)*8
  const u16* wthr = WT + (size_t)h32 * 2048 + (size_t)(ng * 64 + l31) * 8;

  int cur = 0;
#pragma unroll 1
  for (int ch = 0; ch < NC; ++ch) {
    if (ch + 1 < NC) stage(ch + 1, cur ^ 1);
    const char* lb = (const char*)&lds[cur][0];
    const u16* wch = wthr + (size_t)ch * 8 * 2048;
#pragma unroll
    for (int t = 0; t < 9; ++t) {
      const int dy = t / 3, dx = t - (t / 3) * 3;
      short8 wfr[4][2];
#pragma unroll
      for (int kk = 0; kk < 4; ++kk)
#pragma unroll
        for (int f = 0; f < 2; ++f)
          wfr[kk][f] = *(const short8*)(wch + (size_t)(t * (ICT / 8) + kk * 2) * 2048 +
                                        f * 256);
#pragma unroll
      for (int kk = 0; kk < 4; ++kk) {
        short8 bfr[2];
#pragma unroll
        for (int i = 0; i < 2; ++i) {
          int rr = rg[i] + dy * 9 + dx;
          int byt = (rr * 128 + kk * 32 + h32 * 16) ^ ((rr & 7) << 4);
          bfr[i] = *(const short8*)(lb + byt);
        }
        __builtin_amdgcn_s_setprio(1);
#pragma unroll
        for (int i = 0; i < 2; ++i)
#pragma unroll
          for (int f = 0; f < 2; ++f)
            acc[i][f] = FIRST
                ? __builtin_amdgcn_mfma_f32_32x32x16_bf16(bfr[i], wfr[kk][f],
                                                          acc[i][f], 0, 0, 0)
                : __builtin_amdgcn_mfma_f32_32x32x16_bf16(wfr[kk][f], bfr[i],
                                                          acc[i][f], 0, 0, 0);
        __builtin_amdgcn_s_setprio(0);
      }
    }
    __syncthreads();  // drains global_load_lds for next buffer
    cur ^= 1;
  }

  // D mapping (32x32): col = lane&31, row = (reg&3) + 8*(reg>>2) + 4*(lane>>5)
  if (FIRST) {
    // D row = pixel, col = oc
    u16* ob = OUT + (size_t)ba2 * 81 * 256;
#pragma unroll
    for (int f = 0; f < 2; ++f) {
      int oc = ng * 64 + f * 32 + l31;
      float s = sb[oc], bb = sb[256 + oc];
#pragma unroll
      for (int i = 0; i < 2; ++i) {
        int tl = mg * 2 + i;
#pragma unroll
        for (int reg = 0; reg < 16; ++reg) {
          int m = (reg & 3) + 8 * (reg >> 2) + 4 * h32;
          int P = tl * 32 + m;
          if (P < 98) {
            int roi = (P >= 49) ? 1 : 0;
            int q = P - roi * 49;
            int pp = (q / 7 + 1) * 9 + (q - (q / 7) * 7) + 1;
            ob[((size_t)roi * 81 + pp) * 256 + oc] =
                f2bf(fmaxf(acc[i][f][reg] * s + bb, 0.0f));
          }
        }
      }
    }
  } else {
    // D row = oc, col = pixel
    u16* ob = OUT + (size_t)ba2 * 256 * 49;
#pragma unroll
    for (int i = 0; i < 2; ++i) {
      int tl = mg * 2 + i;
      int P = tl * 32 + l31;
      if (P < 98) {
        int roi = (P >= 49) ? 1 : 0;
        int q = P - roi * 49;
#pragma unroll
        for (int f = 0; f < 2; ++f)
#pragma unroll
          for (int reg = 0; reg < 16; ++reg) {
            int oc = ng * 64 + f * 32 + (reg & 3) + 8 * (reg >> 2) + 4 * h32;
            float s = sb[oc], bb = sb[256 + oc];
            ob[((size_t)roi * 256 + oc) * 49 + q] =
                f2bf(fmaxf(acc[i][f][reg] * s + bb, 0.0f));
          }
      }
    }
  }
}

// ---- head: 1x1(256->64)+ReLU -> 1x1(64->2) -> softmax -> blend ------------
__global__ __launch_bounds__(256)
void k_head_fuse(const u16* __restrict__ x3, const u16* __restrict__ cat,
                 const float* __restrict__ w1, const float* __restrict__ b1,
                 const float* __restrict__ w2, const float* __restrict__ b2,
                 float* __restrict__ out) {
  int ba  = blockIdx.x;
  int tid = threadIdx.x;
  __shared__ float xs[256 * 49];
  __shared__ float hs[64 * 49];
  __shared__ float ls[2 * 49];
  __shared__ float swx[2 * 49];
  const u16* src = x3 + (size_t)ba * 256 * 49;
  for (int idx = tid; idx < 256 * 49; idx += 256) xs[idx] = bf2f(src[idx]);
  __syncthreads();
  for (int idx = tid; idx < 64 * 49; idx += 256) {
    int oh = idx / 49, p = idx - oh * 49;
    float s = b1[oh];
    const float* wr = w1 + oh * 256;
    for (int ic = 0; ic < 256; ++ic) s += wr[ic] * xs[ic * 49 + p];
    hs[idx] = fmaxf(s, 0.0f);
  }
  __syncthreads();
  if (tid < 98) {
    int chn = tid / 49, p = tid - chn * 49;
    float s = b2[chn];
    const float* wr = w2 + chn * 64;
    for (int k = 0; k < 64; ++k) s += wr[k] * hs[k * 49 + p];
    ls[tid] = s;
  }
  __syncthreads();
  if (tid < 49) {
    float l0 = ls[tid], l1 = ls[49 + tid];
    float m = fmaxf(l0, l1);
    float e0 = expf(l0 - m), e1 = expf(l1 - m);
    float d = e0 + e1;
    swx[tid]      = e0 / d;
    swx[49 + tid] = e1 / d;
  }
  __syncthreads();
  const u16* cr = cat + (size_t)ba * 81 * 512;
  float* o = out + (size_t)ba * 256 * 49;
  for (int idx = tid; idx < 256 * 49; idx += 256) {
    int c = idx / 49, p = idx - (idx / 49) * 49;
    int pp = (p / 7 + 1) * 9 + (p - (p / 7) * 7) + 1;
    float rgb = bf2f(cr[pp * 512 + c]);
    float tir = bf2f(cr[pp * 512 + 256 + c]);
    o[idx] = swx[p] * rgb + swx[49 + p] * tir;
  }
}

// ---------------------------------------------------------------------------
extern "C" void kernel_launch(void* const* d_in, const int* in_sizes, int n_in,
                              void* d_out, int out_size, void* d_ws, size_t ws_size,
                              hipStream_t stream) {
  const float* feat_rgb = (const float*)d_in[0];
  const float* feat_tir = (const float*)d_in[1];
  const int*   coords   = (const int*)d_in[2];
  const float* conv1_w  = (const float*)d_in[3];
  const float* conv1_b  = (const float*)d_in[4];
  const float* bn1_s    = (const float*)d_in[5];
  const float* bn1_b    = (const float*)d_in[6];
  const float* bn1_m    = (const float*)d_in[7];
  const float* bn1_v    = (const float*)d_in[8];
  const float* conv2_w  = (const float*)d_in[9];
  const float* conv2_b  = (const float*)d_in[10];
  const float* bn2_s    = (const float*)d_in[11];
  const float* bn2_b    = (const float*)d_in[12];
  const float* bn2_m    = (const float*)d_in[13];
  const float* bn2_v    = (const float*)d_in[14];
  const float* wg1_w    = (const float*)d_in[15];
  const float* wg1_b    = (const float*)d_in[16];
  const float* wg2_w    = (const float*)d_in[17];
  const float* wg2_b    = (const float*)d_in[18];
  float* out = (float*)d_out;

  // workspace layout (bytes)
  char* base = (char*)d_ws;
  u16*   W1T  = (u16*)(base);                       //  2,359,296 B
  u16*   W2T  = (u16*)(base + 2359296);             //  1,179,648 B
  float* SB1  = (float*)(base + 2359296 + 1179648); //      2,048 B
  float* SB2  = (float*)(base + 2359296 + 1179648 + 2048);
  u16*   CAT2 = (u16*)(base + 2359296 + 1179648 + 4096);                       // 84,934,656 B
  u16*   X2   = (u16*)(base + 2359296 + 1179648 + 4096 + 84934656);            // 42,467,328 B
  u16*   X3   = (u16*)(base + 2359296 + 1179648 + 4096 + 84934656 + 42467328); // 25,690,112 B
  // total ~156.6 MB

  k_prep_w<512><<<(9 * 256 * 512 + 255) / 256, 256, 0, stream>>>(conv1_w, W1T);
  k_prep_w<256><<<(9 * 256 * 256 + 255) / 256, 256, 0, stream>>>(conv2_w, W2T);
  k_prep_bn<<<1, 256, 0, stream>>>(conv1_b, bn1_s, bn1_b, bn1_m, bn1_v, SB1);
  k_prep_bn<<<1, 256, 0, stream>>>(conv2_b, bn2_s, bn2_b, bn2_m, bn2_v, SB2);
  k_roi2<<<1024, 256, 0, stream>>>(feat_rgb, feat_tir, coords, CAT2);
  k_conv_mfma<512, true><<<512, 512, 0, stream>>>(CAT2, W1T, SB1, X2);
  k_conv_mfma<256, false><<<512, 512, 0, stream>>>(X2, W2T, SB2, X3);
  k_head_fuse<<<1024, 256, 0, stream>>>(X3, CAT2, wg1_w, wg1_b, wg2_w, wg2_b, out);
}